// Round 17
// baseline (78.735 us; speedup 1.0000x reference)
//
#include <hip/hip_runtime.h>
#include <stdint.h>

typedef unsigned short u16;
typedef __attribute__((ext_vector_type(8))) __bf16 bf16x8;
typedef __attribute__((ext_vector_type(4))) __bf16 bf16x4;
typedef __attribute__((ext_vector_type(4))) float f32x4;

#define S_LEN 2048
#define EMB   1024
#define NH    16
#define NKV   4
#define HD    64
#define WIN   256
#define NB    2
#define MROWS (NB * S_LEN)   // 4096
#define PPAD  72             // P LDS row stride (elements)

// ---------- helpers ----------
__device__ __forceinline__ u16 f2bf(float f) {
    uint32_t u = __float_as_uint(f);
    uint32_t r = (u + 0x7FFFu + ((u >> 16) & 1u)) >> 16;   // RNE
    return (u16)r;
}

__device__ __forceinline__ float fast_exp2(float x) {
#if __has_builtin(__builtin_amdgcn_exp2f)
    return __builtin_amdgcn_exp2f(x);
#else
    float r; asm("v_exp_f32 %0, %1" : "=v"(r) : "v"(x)); return r;
#endif
}

__device__ __forceinline__ void gload16(const void* g, void* l) {
    __builtin_amdgcn_global_load_lds(
        (const __attribute__((address_space(1))) uint32_t*)(uintptr_t)g,
        (__attribute__((address_space(3))) uint32_t*)(uintptr_t)l,
        16, 0, 0);
}

// ---------- weight transpose job (shared-buffer passed in) ----------
// in [R][C] f32 -> out [C][R] bf16; tile = 64 rows (r) x 32 cols (c)
__device__ __forceinline__ void transpose_job64(const float* __restrict__ in,
                                                u16* __restrict__ out,
                                                int R, int C, int bx, int by, int tid,
                                                float (*t)[33]) {
    int c0 = bx * 32, r0 = by * 64;
    int tx = tid & 31, ty = tid >> 5;   // (32, 8)
#pragma unroll
    for (int j = 0; j < 64; j += 8)
        t[ty + j][tx] = in[(size_t)(r0 + ty + j) * C + (c0 + tx)];
    __syncthreads();
#pragma unroll
    for (int j = 0; j < 32; j += 8) {
        int c = j + ty;
        uint32_t v = f2bf(t[2 * tx][c]) | ((uint32_t)f2bf(t[2 * tx + 1][c]) << 16);
        *(uint32_t*)(out + (size_t)(c0 + c) * R + r0 + 2 * tx) = v;
    }
}

// ---------- prep: x->bf16 + wq/wk/wv transposes (wo^T in attn spare blocks) ----------
// grid 2816: [0,2048) x-cvt; [2048,2560) wq^T; [2560,2688) wk^T; [2688,2816) wv^T
__global__ __launch_bounds__(256) void prep_kernel(
    const float* __restrict__ x,  const float* __restrict__ wq,
    const float* __restrict__ wk, const float* __restrict__ wv,
    u16* __restrict__ xb, u16* __restrict__ wqt, u16* __restrict__ wkt,
    u16* __restrict__ wvt) {
    __shared__ float t[64][33];
    int bid = blockIdx.x, tid = threadIdx.x;
    if (bid < 2048) {
        int i = bid * 256 + tid;                       // 8 elems each
        const float4* p = (const float4*)x + (size_t)i * 2;
        float4 a = p[0], b = p[1];
        uint4 q;
        q.x = f2bf(a.x) | ((uint32_t)f2bf(a.y) << 16);
        q.y = f2bf(a.z) | ((uint32_t)f2bf(a.w) << 16);
        q.z = f2bf(b.x) | ((uint32_t)f2bf(b.y) << 16);
        q.w = f2bf(b.z) | ((uint32_t)f2bf(b.w) << 16);
        ((uint4*)xb)[i] = q;
    } else if (bid < 2560) {
        int lb = bid - 2048;  transpose_job64(wq, wqt, EMB, EMB, lb & 31, lb >> 5, tid, t);
    } else if (bid < 2688) {
        int lb = bid - 2560;  transpose_job64(wk, wkt, EMB, 256, lb & 7, lb >> 3, tid, t);
    } else {
        int lb = bid - 2688;  transpose_job64(wv, wvt, EMB, 256, lb & 7, lb >> 3, tid, t);
    }
}

// ---------- GEMM core: BM=64 x BN=128, BK=64 (kept for gemm_out) ----------
__device__ __forceinline__ void gemm_core64(const __bf16* __restrict__ A, const __bf16* __restrict__ Bt,
                                            int K, int m0, int n0r,
                                            __bf16 (*As)[64 * 64], __bf16 (*Bs)[128 * 64],
                                            f32x4 (&acc)[2][4], int tid) {
    const int lane = tid & 63, w = tid >> 6;
    const int wr = w >> 1, wc = w & 1;
    const int r = lane & 15, g = lane >> 4;

    auto stage = [&](int buf, int k0) {
#pragma unroll
        for (int i = 0; i < 2; ++i) {
            int chunk = (w * 2 + i) * 64 + lane;
            int row = chunk >> 3, cc = chunk & 7;
            gload16(A + (size_t)(m0 + row) * K + k0 + cc * 8, &As[buf][(w * 2 + i) * 512]);
        }
#pragma unroll
        for (int i = 0; i < 4; ++i) {
            int chunk = (w * 4 + i) * 64 + lane;
            int row = chunk >> 3, cc = chunk & 7;
            gload16(Bt + (size_t)(n0r + row) * K + k0 + cc * 8, &Bs[buf][(w * 4 + i) * 512]);
        }
    };

    stage(0, 0);
    __syncthreads();
    for (int k0 = 0; k0 < K; k0 += 64) {
        int cur = (k0 >> 6) & 1;
        if (k0 + 64 < K) stage(cur ^ 1, k0 + 64);
        bf16x8 af[2][2], bfr[4][2];
#pragma unroll
        for (int mf = 0; mf < 2; ++mf)
#pragma unroll
            for (int kk = 0; kk < 2; ++kk)
                af[mf][kk] = *(const bf16x8*)(&As[cur][(wr * 32 + mf * 16 + r) * 64 + kk * 32 + g * 8]);
#pragma unroll
        for (int nf = 0; nf < 4; ++nf)
#pragma unroll
            for (int kk = 0; kk < 2; ++kk)
                bfr[nf][kk] = *(const bf16x8*)(&Bs[cur][(wc * 64 + nf * 16 + r) * 64 + kk * 32 + g * 8]);
#pragma unroll
        for (int mf = 0; mf < 2; ++mf)
#pragma unroll
            for (int nf = 0; nf < 4; ++nf)
#pragma unroll
                for (int kk = 0; kk < 2; ++kk)
                    acc[mf][nf] = __builtin_amdgcn_mfma_f32_16x16x32_bf16(
                        af[mf][kk], bfr[nf][kk], acc[mf][nf], 0, 0, 0);
        __syncthreads();
    }
}

// ---------- QKV projection: BM=32 x BN=128, BK=32, 6 blocks/CU latency-depth ----------
// grid 1536 = 8 XCD x 192; job: n-tile = wg%12 (0-7 Q, 8-9 K, 10-11 V), m-tile = 32 rows
__global__ __launch_bounds__(256, 6) void gemm_qkv_kernel(
    const __bf16* __restrict__ xb, const __bf16* __restrict__ wqt,
    const __bf16* __restrict__ wkt, const __bf16* __restrict__ wvt,
    const float* __restrict__ bq, const float* __restrict__ bk, const float* __restrict__ bv,
    __bf16* __restrict__ Qb, __bf16* __restrict__ Kb, __bf16* __restrict__ Vblk) {
    __shared__ __align__(16) __bf16 As[2][32 * 32];    // 2KB per buf
    __shared__ __align__(16) __bf16 Bs[2][128 * 32];   // 8KB per buf
    int tid = threadIdx.x;
    const int lane = tid & 63, w = tid >> 6;
    const int wr = w >> 1, wc = w & 1;
    const int r = lane & 15, g = lane >> 4;
    int wg = (blockIdx.x & 7) * 192 + (blockIdx.x >> 3);   // 1536 = 8 XCD x 192
    int n0 = (wg % 12) * 128, m0 = (wg / 12) * 32;

    const __bf16* Bt; int n0r; const float* bias; int mode;
    if (n0 < 1024)      { Bt = wqt; n0r = n0;        bias = bq; mode = 0; }
    else if (n0 < 1280) { Bt = wkt; n0r = n0 - 1024; bias = bk; mode = 1; }
    else                { Bt = wvt; n0r = n0 - 1280; bias = bv; mode = 2; }

    // staging: 10 wave-calls per step (calls 0-1 = A 2KB, calls 2-9 = B 8KB)
    auto stage = [&](int buf, int k0) {
#pragma unroll
        for (int i = 0; i < 3; ++i) {
            int c = w + i * 4;
            if (c < 2) {
                int n = c * 64 + lane;
                int row = n >> 2, cc = n & 3;
                gload16(xb + (size_t)(m0 + row) * EMB + k0 + cc * 8, &As[buf][c * 512]);
            } else if (c < 10) {
                int n = (c - 2) * 64 + lane;
                int row = n >> 2, cc = n & 3;
                gload16(Bt + (size_t)(n0r + row) * EMB + k0 + cc * 8, &Bs[buf][(c - 2) * 512]);
            }
        }
    };

    f32x4 acc[4];
    f32x4 z = {0.f, 0.f, 0.f, 0.f};
#pragma unroll
    for (int j = 0; j < 4; ++j) acc[j] = z;

    stage(0, 0);
    __syncthreads();
    for (int k0 = 0; k0 < EMB; k0 += 32) {
        int cur = (k0 >> 5) & 1;
        if (k0 + 32 < EMB) stage(cur ^ 1, k0 + 32);
        bf16x8 af = *(const bf16x8*)(&As[cur][(wr * 16 + r) * 32 + g * 8]);
        bf16x8 bfr[4];
#pragma unroll
        for (int nf = 0; nf < 4; ++nf)
            bfr[nf] = *(const bf16x8*)(&Bs[cur][(wc * 64 + nf * 16 + r) * 32 + g * 8]);
#pragma unroll
        for (int nf = 0; nf < 4; ++nf)
            acc[nf] = __builtin_amdgcn_mfma_f32_16x16x32_bf16(af, bfr[nf], acc[nf], 0, 0, 0);
        __syncthreads();
    }

    // epilogue: out row = m0 + wr*16 + g*4 + reg, col = n0r + wc*64 + nf*16 + r
#pragma unroll
    for (int nf = 0; nf < 4; ++nf) {
        int nn = n0r + wc * 64 + nf * 16 + r;
        float bb = bias[nn];
        int hh = nn >> 6, dd = nn & 63;
        if (mode == 2) {
            int s0 = m0 + wr * 16 + g * 4;
            int bi = s0 >> 11, s = s0 & 2047;
            bf16x4 pk;
#pragma unroll
            for (int reg = 0; reg < 4; ++reg) pk[reg] = (__bf16)(acc[nf][reg] + bb);
            *reinterpret_cast<bf16x4*>(Vblk + (size_t)(bi * NKV + hh) * (S_LEN * HD)
                                       + (s >> 6) * 4096 + dd * 64 + (s & 63)) = pk;
        } else {
#pragma unroll
            for (int reg = 0; reg < 4; ++reg) {
                int m = m0 + wr * 16 + g * 4 + reg;
                int bi = m >> 11, s = m & 2047;
                __bf16 o = (__bf16)(acc[nf][reg] + bb);
                if (mode == 0)
                    Qb[((size_t)(bi * NH + hh) * S_LEN + s) * HD + dd] = o;
                else
                    Kb[((size_t)(bi * NKV + hh) * S_LEN + s) * HD + dd] = o;
            }
        }
    }
}

// ---------- sliding-window flash attention: QBLK=128 + wave tile-skip + wot^T in spare blocks ----------
// 1D grid 768: bid<512 -> attn job; bid>=512 -> 2 wo-transpose jobs each
__global__ __launch_bounds__(256, 3) void attn_kernel(const __bf16* __restrict__ Qb,
                                                      const __bf16* __restrict__ Kb,
                                                      const __bf16* __restrict__ Vblk,
                                                      const float* __restrict__ wo,
                                                      u16* __restrict__ wot,
                                                      __bf16* __restrict__ ctx) {
    __shared__ __align__(16) __bf16 Ks[2][64 * 64];      // [buf][row=key][d]  8KB each
    __shared__ __align__(16) __bf16 Vs[2][64 * 64];      // [buf][row=d][key]  8KB each
    __shared__ __align__(16) __bf16 Plds[4][32 * PPAD];  // per-wave P [q=32][k=64 pad]
    const int tid = threadIdx.x;
    const int bid = blockIdx.x;

    if (bid >= 512) {
        float (*t)[33] = reinterpret_cast<float(*)[33]>(&Ks[0][0]);   // 8.5KB <= 16KB
        int j0 = (bid - 512) * 2;
        transpose_job64(wo, wot, EMB, EMB, j0 & 31, j0 >> 5, tid, t);
        __syncthreads();
        int j1 = j0 + 1;
        transpose_job64(wo, wot, EMB, EMB, j1 & 31, j1 >> 5, tid, t);
        return;
    }

    const int lane = tid & 63, w = tid >> 6;
    const int r = lane & 15, g = lane >> 4;
    const int q0 = (bid & 15) * 128;
    const int h = (bid >> 4) & 15, b = bid >> 8;
    const int kvh = h >> 2;
    const __bf16* Kh = Kb + (size_t)(b * NKV + kvh) * S_LEN * HD;
    const __bf16* Vh = Vblk + (size_t)(b * NKV + kvh) * S_LEN * HD;
    __bf16* Pw = &Plds[w][0];

    const int n0s = w * 128 + lane;
    const int n1s = n0s + 64;
    const int srcoff0 = (n0s >> 3) * 64 + (((n0s & 7) ^ ((n0s >> 3) & 7)) * 8);
    const int srcoff1 = (n1s >> 3) * 64 + (((n1s & 7) ^ ((n1s >> 3) & 7)) * 8);
    const int dst0 = (w * 2) * 512;
    const int dst1 = dst0 + 512;

    auto stage = [&](int buf, int kbase) {
        const __bf16* Kt = Kh + (size_t)kbase * 64;
        const __bf16* Vt = Vh + (size_t)kbase * 64;
        gload16(Kt + srcoff0, &Ks[buf][dst0]);
        gload16(Kt + srcoff1, &Ks[buf][dst1]);
        gload16(Vt + srcoff0, &Vs[buf][dst0]);
        gload16(Vt + srcoff1, &Vs[buf][dst1]);
    };

    const int swz0 = ((0 * 4 + g) ^ (r & 7)) * 8;
    const int swz1 = ((1 * 4 + g) ^ (r & 7)) * 8;

    bf16x8 qf[2][2];
#pragma unroll
    for (int gq = 0; gq < 2; ++gq)
#pragma unroll
        for (int kk = 0; kk < 2; ++kk)
            qf[gq][kk] = *(const bf16x8*)(Qb + ((size_t)(b * NH + h) * S_LEN
                                          + q0 + w * 32 + gq * 16 + r) * HD + kk * 32 + g * 8);

    f32x4 z = {0.f, 0.f, 0.f, 0.f};
    f32x4 o[2][4];
#pragma unroll
    for (int gq = 0; gq < 2; ++gq)
#pragma unroll
        for (int i = 0; i < 4; ++i) o[gq][i] = z;
    float psum[2] = {0.f, 0.f};

    const float SC = 0.18033688011112042f;   // D^-0.5 * log2(e)
    int iq[2];
#pragma unroll
    for (int gq = 0; gq < 2; ++gq) iq[gq] = q0 + w * 32 + gq * 16 + r;

    auto tile = [&](int buf, int kbase) {
        const __bf16* Kl = &Ks[buf][0];
        const __bf16* Vl = &Vs[buf][0];
        f32x4 sa[2][4];
#pragma unroll
        for (int gq = 0; gq < 2; ++gq)
#pragma unroll
            for (int nf = 0; nf < 4; ++nf) sa[gq][nf] = z;
#pragma unroll
        for (int nf = 0; nf < 4; ++nf) {
            bf16x8 kf0 = *(const bf16x8*)(Kl + nf * 1024 + r * 64 + swz0);
            bf16x8 kf1 = *(const bf16x8*)(Kl + nf * 1024 + r * 64 + swz1);
            sa[0][nf] = __builtin_amdgcn_mfma_f32_16x16x32_bf16(kf0, qf[0][0], sa[0][nf], 0, 0, 0);
            sa[1][nf] = __builtin_amdgcn_mfma_f32_16x16x32_bf16(kf0, qf[1][0], sa[1][nf], 0, 0, 0);
            sa[0][nf] = __builtin_amdgcn_mfma_f32_16x16x32_bf16(kf1, qf[0][1], sa[0][nf], 0, 0, 0);
            sa[1][nf] = __builtin_amdgcn_mfma_f32_16x16x32_bf16(kf1, qf[1][1], sa[1][nf], 0, 0, 0);
        }
#pragma unroll
        for (int gq = 0; gq < 2; ++gq)
#pragma unroll
            for (int nf = 0; nf < 4; ++nf) {
                int jb = kbase + nf * 16 + g * 4;
                bf16x4 pk;
#pragma unroll
                for (int reg = 0; reg < 4; ++reg) {
                    float x = sa[gq][nf][reg] * SC;
                    uint32_t d = (uint32_t)(iq[gq] - (jb + reg));   // valid iff 0 <= iq-j <= WIN
                    x = (d <= (uint32_t)WIN) ? x : -1e30f;
                    float e = fast_exp2(x);
                    psum[gq] += e;
                    pk[reg] = (__bf16)e;
                }
                *reinterpret_cast<bf16x4*>(Pw + gq * 16 * PPAD + r * PPAD + nf * 16 + g * 4) = pk;
            }
#pragma unroll
        for (int kk2 = 0; kk2 < 2; ++kk2) {
            bf16x8 pa0 = *(const bf16x8*)(Pw + r * PPAD + kk2 * 32 + g * 8);
            bf16x8 pa1 = *(const bf16x8*)(Pw + 16 * PPAD + r * PPAD + kk2 * 32 + g * 8);
            int sw = kk2 ? swz1 : swz0;
#pragma unroll
            for (int nf2 = 0; nf2 < 4; ++nf2) {
                bf16x8 vf = *(const bf16x8*)(Vl + nf2 * 1024 + r * 64 + sw);
                o[0][nf2] = __builtin_amdgcn_mfma_f32_16x16x32_bf16(vf, pa0, o[0][nf2], 0, 0, 0);
                o[1][nf2] = __builtin_amdgcn_mfma_f32_16x16x32_bf16(vf, pa1, o[1][nf2], 0, 0, 0);
            }
        }
    };

    const int kb0 = (q0 >= 256) ? (q0 - 256) : 0;
    const int nt = (q0 + 64 - kb0) / 64 + 1;    // up to 6 tiles; keys [kb0, q0+128)
    stage(0, kb0);
    __syncthreads();
    for (int tt = 0; tt < nt; ++tt) {
        int kbase = kb0 + tt * 64;
        if (tt + 1 < nt) stage((tt + 1) & 1, kbase + 64);
        // wave-level full-mask skip (exact)
        bool skip = (tt == 0 && q0 >= 256 && w >= 2) || (tt == nt - 1 && w < 2);
        if (!skip) tile(tt & 1, kbase);
        __syncthreads();
    }

#pragma unroll
    for (int gq = 0; gq < 2; ++gq) {
        psum[gq] += __shfl_xor(psum[gq], 16, 64);
        psum[gq] += __shfl_xor(psum[gq], 32, 64);
        float linv = 1.0f / psum[gq];
        int s = q0 + w * 32 + gq * 16 + r;
#pragma unroll
        for (int nf2 = 0; nf2 < 4; ++nf2) {
            bf16x4 pk;
#pragma unroll
            for (int reg = 0; reg < 4; ++reg) pk[reg] = (__bf16)(o[gq][nf2][reg] * linv);
            *reinterpret_cast<bf16x4*>(ctx + ((size_t)(b * S_LEN + s)) * EMB
                                       + h * 64 + nf2 * 16 + g * 4) = pk;
        }
    }
}

// ---------- output projection (r9 form) ----------
__global__ __launch_bounds__(256, 3) void gemm_out_kernel(const __bf16* __restrict__ ctxb,
                                                          const __bf16* __restrict__ wot,
                                                          const float* __restrict__ bo,
                                                          float* __restrict__ out) {
    __shared__ __align__(16) __bf16 As[2][64 * 64];
    __shared__ __align__(16) __bf16 Bs[2][128 * 64];
    int tid = threadIdx.x;
    int wg = (blockIdx.x & 7) * 64 + (blockIdx.x >> 3);   // 512 = 8 XCD x 64
    int n0 = (wg % 8) * 128, m0 = (wg / 8) * 64;

    f32x4 acc[2][4];
    f32x4 z = {0.f, 0.f, 0.f, 0.f};
#pragma unroll
    for (int i = 0; i < 2; ++i)
#pragma unroll
        for (int j = 0; j < 4; ++j) acc[i][j] = z;

    gemm_core64(ctxb, wot, EMB, m0, n0, As, Bs, acc, tid);

    const int lane = tid & 63, w = tid >> 6;
    const int wr = w >> 1, wc = w & 1, r = lane & 15, g = lane >> 4;
#pragma unroll
    for (int nf = 0; nf < 4; ++nf) {
        int n = n0 + wc * 64 + nf * 16 + r;
        float bb = bo[n];
#pragma unroll
        for (int mf = 0; mf < 2; ++mf)
#pragma unroll
            for (int reg = 0; reg < 4; ++reg) {
                int m = m0 + wr * 32 + mf * 16 + g * 4 + reg;
                out[(size_t)m * EMB + n] = acc[mf][nf][reg] + bb;
            }
    }
}

// ---------- launch ----------
extern "C" void kernel_launch(void* const* d_in, const int* in_sizes, int n_in,
                              void* d_out, int out_size, void* d_ws, size_t ws_size,
                              hipStream_t stream) {
    const float* x  = (const float*)d_in[0];
    const float* wq = (const float*)d_in[1];
    const float* bq = (const float*)d_in[2];
    const float* wk = (const float*)d_in[3];
    const float* bk = (const float*)d_in[4];
    const float* wv = (const float*)d_in[5];
    const float* bv = (const float*)d_in[6];
    const float* wo = (const float*)d_in[7];
    const float* bo = (const float*)d_in[8];
    float* out = (float*)d_out;

    char* ws = (char*)d_ws;
    __bf16* xb   = (__bf16*)ws;          ws += (size_t)MROWS * EMB * 2;           // 8 MB
    __bf16* wqt  = (__bf16*)ws;          ws += (size_t)EMB * EMB * 2;             // 2 MB
    __bf16* wkt  = (__bf16*)ws;          ws += (size_t)256 * EMB * 2;             // 0.5 MB
    __bf16* wvt  = (__bf16*)ws;          ws += (size_t)256 * EMB * 2;             // 0.5 MB
    __bf16* wot  = (__bf16*)ws;          ws += (size_t)EMB * EMB * 2;             // 2 MB
    __bf16* Qb   = (__bf16*)ws;          ws += (size_t)NB * NH * S_LEN * HD * 2;  // 8 MB
    __bf16* Kb   = (__bf16*)ws;          ws += (size_t)NB * NKV * S_LEN * HD * 2; // 2 MB
    __bf16* Vblk = (__bf16*)ws;          ws += (size_t)NB * NKV * S_LEN * HD * 2; // 2 MB
    __bf16* ctx  = (__bf16*)ws;          ws += (size_t)MROWS * EMB * 2;           // 8 MB

    prep_kernel<<<2816, 256, 0, stream>>>(x, wq, wk, wv,
                                          (u16*)xb, (u16*)wqt, (u16*)wkt, (u16*)wvt);
    gemm_qkv_kernel<<<1536, 256, 0, stream>>>(xb, wqt, wkt, wvt, bq, bk, bv, Qb, Kb, Vblk);
    attn_kernel<<<768, 256, 0, stream>>>(Qb, Kb, Vblk, wo, (u16*)wot, ctx);
    gemm_out_kernel<<<512, 256, 0, stream>>>(ctx, wot, bo, out);
}

// Round 18
// 63.952 us; speedup vs baseline: 1.2311x; 1.2311x over previous
//
#include <hip/hip_runtime.h>
#include <stdint.h>

typedef unsigned short u16;
typedef __attribute__((ext_vector_type(8))) __bf16 bf16x8;
typedef __attribute__((ext_vector_type(4))) __bf16 bf16x4;
typedef __attribute__((ext_vector_type(4))) float f32x4;

#define S_LEN 2048
#define EMB   1024
#define NH    16
#define NKV   4
#define HD    64
#define WIN   256
#define NB    2
#define MROWS (NB * S_LEN)   // 4096
#define PPAD  72             // P LDS row stride (elements)

// ---------- helpers ----------
__device__ __forceinline__ u16 f2bf(float f) {
    uint32_t u = __float_as_uint(f);
    uint32_t r = (u + 0x7FFFu + ((u >> 16) & 1u)) >> 16;   // RNE
    return (u16)r;
}

__device__ __forceinline__ float fast_exp2(float x) {
#if __has_builtin(__builtin_amdgcn_exp2f)
    return __builtin_amdgcn_exp2f(x);
#else
    float r; asm("v_exp_f32 %0, %1" : "=v"(r) : "v"(x)); return r;
#endif
}

__device__ __forceinline__ void gload16(const void* g, void* l) {
    __builtin_amdgcn_global_load_lds(
        (const __attribute__((address_space(1))) uint32_t*)(uintptr_t)g,
        (__attribute__((address_space(3))) uint32_t*)(uintptr_t)l,
        16, 0, 0);
}

// ---------- weight transpose job (shared-buffer passed in) ----------
// in [R][C] f32 -> out [C][R] bf16; tile = 64 rows (r) x 32 cols (c)
__device__ __forceinline__ void transpose_job64(const float* __restrict__ in,
                                                u16* __restrict__ out,
                                                int R, int C, int bx, int by, int tid,
                                                float (*t)[33]) {
    int c0 = bx * 32, r0 = by * 64;
    int tx = tid & 31, ty = tid >> 5;   // (32, 8)
#pragma unroll
    for (int j = 0; j < 64; j += 8)
        t[ty + j][tx] = in[(size_t)(r0 + ty + j) * C + (c0 + tx)];
    __syncthreads();
#pragma unroll
    for (int j = 0; j < 32; j += 8) {
        int c = j + ty;
        uint32_t v = f2bf(t[2 * tx][c]) | ((uint32_t)f2bf(t[2 * tx + 1][c]) << 16);
        *(uint32_t*)(out + (size_t)(c0 + c) * R + r0 + 2 * tx) = v;
    }
}

// ---------- prep: x->bf16 + wq/wk/wv transposes (wo^T in attn spare blocks) ----------
// grid 2816: [0,2048) x-cvt; [2048,2560) wq^T; [2560,2688) wk^T; [2688,2816) wv^T
__global__ __launch_bounds__(256) void prep_kernel(
    const float* __restrict__ x,  const float* __restrict__ wq,
    const float* __restrict__ wk, const float* __restrict__ wv,
    u16* __restrict__ xb, u16* __restrict__ wqt, u16* __restrict__ wkt,
    u16* __restrict__ wvt) {
    __shared__ float t[64][33];
    int bid = blockIdx.x, tid = threadIdx.x;
    if (bid < 2048) {
        int i = bid * 256 + tid;                       // 8 elems each
        const float4* p = (const float4*)x + (size_t)i * 2;
        float4 a = p[0], b = p[1];
        uint4 q;
        q.x = f2bf(a.x) | ((uint32_t)f2bf(a.y) << 16);
        q.y = f2bf(a.z) | ((uint32_t)f2bf(a.w) << 16);
        q.z = f2bf(b.x) | ((uint32_t)f2bf(b.y) << 16);
        q.w = f2bf(b.z) | ((uint32_t)f2bf(b.w) << 16);
        ((uint4*)xb)[i] = q;
    } else if (bid < 2560) {
        int lb = bid - 2048;  transpose_job64(wq, wqt, EMB, EMB, lb & 31, lb >> 5, tid, t);
    } else if (bid < 2688) {
        int lb = bid - 2560;  transpose_job64(wk, wkt, EMB, 256, lb & 7, lb >> 3, tid, t);
    } else {
        int lb = bid - 2688;  transpose_job64(wv, wvt, EMB, 256, lb & 7, lb >> 3, tid, t);
    }
}

// ---------- GEMM core: BM=64 x BN=128, BK=64, 4 waves (2x2), 2-phase prefetch ----------
__device__ __forceinline__ void gemm_core64(const __bf16* __restrict__ A, const __bf16* __restrict__ Bt,
                                            int K, int m0, int n0r,
                                            __bf16 (*As)[64 * 64], __bf16 (*Bs)[128 * 64],
                                            f32x4 (&acc)[2][4], int tid) {
    const int lane = tid & 63, w = tid >> 6;
    const int wr = w >> 1, wc = w & 1;
    const int r = lane & 15, g = lane >> 4;

    auto stage = [&](int buf, int k0) {
#pragma unroll
        for (int i = 0; i < 2; ++i) {
            int chunk = (w * 2 + i) * 64 + lane;
            int row = chunk >> 3, cc = chunk & 7;
            gload16(A + (size_t)(m0 + row) * K + k0 + cc * 8, &As[buf][(w * 2 + i) * 512]);
        }
#pragma unroll
        for (int i = 0; i < 4; ++i) {
            int chunk = (w * 4 + i) * 64 + lane;
            int row = chunk >> 3, cc = chunk & 7;
            gload16(Bt + (size_t)(n0r + row) * K + k0 + cc * 8, &Bs[buf][(w * 4 + i) * 512]);
        }
    };

    stage(0, 0);
    __syncthreads();
    for (int k0 = 0; k0 < K; k0 += 64) {
        int cur = (k0 >> 6) & 1;
        if (k0 + 64 < K) stage(cur ^ 1, k0 + 64);
        bf16x8 af[2][2], bfr[4][2];
#pragma unroll
        for (int mf = 0; mf < 2; ++mf)
#pragma unroll
            for (int kk = 0; kk < 2; ++kk)
                af[mf][kk] = *(const bf16x8*)(&As[cur][(wr * 32 + mf * 16 + r) * 64 + kk * 32 + g * 8]);
#pragma unroll
        for (int nf = 0; nf < 4; ++nf)
#pragma unroll
            for (int kk = 0; kk < 2; ++kk)
                bfr[nf][kk] = *(const bf16x8*)(&Bs[cur][(wc * 64 + nf * 16 + r) * 64 + kk * 32 + g * 8]);
#pragma unroll
        for (int mf = 0; mf < 2; ++mf)
#pragma unroll
            for (int nf = 0; nf < 4; ++nf)
#pragma unroll
                for (int kk = 0; kk < 2; ++kk)
                    acc[mf][nf] = __builtin_amdgcn_mfma_f32_16x16x32_bf16(
                        af[mf][kk], bfr[nf][kk], acc[mf][nf], 0, 0, 0);
        __syncthreads();
    }
}

// ---------- QKV projection (r9 form) ----------
__global__ __launch_bounds__(256, 3) void gemm_qkv_kernel(
    const __bf16* __restrict__ xb, const __bf16* __restrict__ wqt,
    const __bf16* __restrict__ wkt, const __bf16* __restrict__ wvt,
    const float* __restrict__ bq, const float* __restrict__ bk, const float* __restrict__ bv,
    __bf16* __restrict__ Qb, __bf16* __restrict__ Kb, __bf16* __restrict__ Vblk) {
    __shared__ __align__(16) __bf16 As[2][64 * 64];
    __shared__ __align__(16) __bf16 Bs[2][128 * 64];
    int tid = threadIdx.x;
    int wg = (blockIdx.x & 7) * 96 + (blockIdx.x >> 3);   // 768 = 8 XCD x 96
    int n0 = (wg % 12) * 128, m0 = (wg / 12) * 64;

    const __bf16* Bt; int n0r; const float* bias; int mode;
    if (n0 < 1024)      { Bt = wqt; n0r = n0;        bias = bq; mode = 0; }
    else if (n0 < 1280) { Bt = wkt; n0r = n0 - 1024; bias = bk; mode = 1; }
    else                { Bt = wvt; n0r = n0 - 1280; bias = bv; mode = 2; }

    f32x4 acc[2][4];
    f32x4 z = {0.f, 0.f, 0.f, 0.f};
#pragma unroll
    for (int i = 0; i < 2; ++i)
#pragma unroll
        for (int j = 0; j < 4; ++j) acc[i][j] = z;

    gemm_core64(xb, Bt, EMB, m0, n0r, As, Bs, acc, tid);

    const int lane = tid & 63, w = tid >> 6;
    const int wr = w >> 1, wc = w & 1, r = lane & 15, g = lane >> 4;
#pragma unroll
    for (int nf = 0; nf < 4; ++nf) {
        int nn = n0r + wc * 64 + nf * 16 + r;
        float bb = bias[nn];
        int hh = nn >> 6, dd = nn & 63;
        if (mode == 2) {
            // block-tiled V: [s>>6][d][s&63]; 4 consecutive s -> 8B store
#pragma unroll
            for (int mf = 0; mf < 2; ++mf) {
                int s0 = m0 + wr * 32 + mf * 16 + g * 4;
                int bi = s0 >> 11, s = s0 & 2047;
                bf16x4 pk;
#pragma unroll
                for (int reg = 0; reg < 4; ++reg) pk[reg] = (__bf16)(acc[mf][nf][reg] + bb);
                *reinterpret_cast<bf16x4*>(Vblk + (size_t)(bi * NKV + hh) * (S_LEN * HD)
                                           + (s >> 6) * 4096 + dd * 64 + (s & 63)) = pk;
            }
        } else {
#pragma unroll
            for (int mf = 0; mf < 2; ++mf)
#pragma unroll
                for (int reg = 0; reg < 4; ++reg) {
                    int m = m0 + wr * 32 + mf * 16 + g * 4 + reg;
                    int bi = m >> 11, s = m & 2047;
                    __bf16 o = (__bf16)(acc[mf][nf][reg] + bb);
                    if (mode == 0)
                        Qb[((size_t)(bi * NH + hh) * S_LEN + s) * HD + dd] = o;
                    else
                        Kb[((size_t)(bi * NKV + hh) * S_LEN + s) * HD + dd] = o;
                }
        }
    }
}

// ---------- sliding-window flash attention: QBLK=128 + wave tile-skip + wot^T in spare blocks ----------
// 1D grid 768: bid<512 -> attn job (qb=bid&15, h=(bid>>4)&15, b=bid>>8);
//              bid>=512 -> 2 wo-transpose jobs each (512 jobs total)
__global__ __launch_bounds__(256, 3) void attn_kernel(const __bf16* __restrict__ Qb,
                                                      const __bf16* __restrict__ Kb,
                                                      const __bf16* __restrict__ Vblk,
                                                      const float* __restrict__ wo,
                                                      u16* __restrict__ wot,
                                                      __bf16* __restrict__ ctx) {
    __shared__ __align__(16) __bf16 Ks[2][64 * 64];      // [buf][row=key][d]  8KB each
    __shared__ __align__(16) __bf16 Vs[2][64 * 64];      // [buf][row=d][key]  8KB each
    __shared__ __align__(16) __bf16 Plds[4][32 * PPAD];  // per-wave P [q=32][k=64 pad]
    const int tid = threadIdx.x;
    const int bid = blockIdx.x;

    if (bid >= 512) {
        // spare blocks: wo [1024][1024] -> wot; 512 tile-jobs, 2 per block
        float (*t)[33] = reinterpret_cast<float(*)[33]>(&Ks[0][0]);   // 8.5KB <= 16KB
        int j0 = (bid - 512) * 2;
        transpose_job64(wo, wot, EMB, EMB, j0 & 31, j0 >> 5, tid, t);
        __syncthreads();
        int j1 = j0 + 1;
        transpose_job64(wo, wot, EMB, EMB, j1 & 31, j1 >> 5, tid, t);
        return;
    }

    const int lane = tid & 63, w = tid >> 6;
    const int r = lane & 15, g = lane >> 4;
    const int q0 = (bid & 15) * 128;
    const int h = (bid >> 4) & 15, b = bid >> 8;
    const int kvh = h >> 2;
    const __bf16* Kh = Kb + (size_t)(b * NKV + kvh) * S_LEN * HD;
    const __bf16* Vh = Vblk + (size_t)(b * NKV + kvh) * S_LEN * HD;
    __bf16* Pw = &Plds[w][0];

    const int n0s = w * 128 + lane;
    const int n1s = n0s + 64;
    const int srcoff0 = (n0s >> 3) * 64 + (((n0s & 7) ^ ((n0s >> 3) & 7)) * 8);
    const int srcoff1 = (n1s >> 3) * 64 + (((n1s & 7) ^ ((n1s >> 3) & 7)) * 8);
    const int dst0 = (w * 2) * 512;
    const int dst1 = dst0 + 512;

    auto stage = [&](int buf, int kbase) {
        const __bf16* Kt = Kh + (size_t)kbase * 64;
        const __bf16* Vt = Vh + (size_t)kbase * 64;
        gload16(Kt + srcoff0, &Ks[buf][dst0]);
        gload16(Kt + srcoff1, &Ks[buf][dst1]);
        gload16(Vt + srcoff0, &Vs[buf][dst0]);
        gload16(Vt + srcoff1, &Vs[buf][dst1]);
    };

    const int swz0 = ((0 * 4 + g) ^ (r & 7)) * 8;
    const int swz1 = ((1 * 4 + g) ^ (r & 7)) * 8;

    bf16x8 qf[2][2];
#pragma unroll
    for (int gq = 0; gq < 2; ++gq)
#pragma unroll
        for (int kk = 0; kk < 2; ++kk)
            qf[gq][kk] = *(const bf16x8*)(Qb + ((size_t)(b * NH + h) * S_LEN
                                          + q0 + w * 32 + gq * 16 + r) * HD + kk * 32 + g * 8);

    f32x4 z = {0.f, 0.f, 0.f, 0.f};
    f32x4 o[2][4];
#pragma unroll
    for (int gq = 0; gq < 2; ++gq)
#pragma unroll
        for (int i = 0; i < 4; ++i) o[gq][i] = z;
    float psum[2] = {0.f, 0.f};

    const float SC = 0.18033688011112042f;   // D^-0.5 * log2(e)
    int iq[2];
#pragma unroll
    for (int gq = 0; gq < 2; ++gq) iq[gq] = q0 + w * 32 + gq * 16 + r;

    auto tile = [&](int buf, int kbase) {
        const __bf16* Kl = &Ks[buf][0];
        const __bf16* Vl = &Vs[buf][0];
        f32x4 sa[2][4];
#pragma unroll
        for (int gq = 0; gq < 2; ++gq)
#pragma unroll
            for (int nf = 0; nf < 4; ++nf) sa[gq][nf] = z;
#pragma unroll
        for (int nf = 0; nf < 4; ++nf) {
            bf16x8 kf0 = *(const bf16x8*)(Kl + nf * 1024 + r * 64 + swz0);
            bf16x8 kf1 = *(const bf16x8*)(Kl + nf * 1024 + r * 64 + swz1);
            sa[0][nf] = __builtin_amdgcn_mfma_f32_16x16x32_bf16(kf0, qf[0][0], sa[0][nf], 0, 0, 0);
            sa[1][nf] = __builtin_amdgcn_mfma_f32_16x16x32_bf16(kf0, qf[1][0], sa[1][nf], 0, 0, 0);
            sa[0][nf] = __builtin_amdgcn_mfma_f32_16x16x32_bf16(kf1, qf[0][1], sa[0][nf], 0, 0, 0);
            sa[1][nf] = __builtin_amdgcn_mfma_f32_16x16x32_bf16(kf1, qf[1][1], sa[1][nf], 0, 0, 0);
        }
#pragma unroll
        for (int gq = 0; gq < 2; ++gq)
#pragma unroll
            for (int nf = 0; nf < 4; ++nf) {
                int jb = kbase + nf * 16 + g * 4;
                bf16x4 pk;
#pragma unroll
                for (int reg = 0; reg < 4; ++reg) {
                    float x = sa[gq][nf][reg] * SC;
                    uint32_t d = (uint32_t)(iq[gq] - (jb + reg));   // valid iff 0 <= iq-j <= WIN
                    x = (d <= (uint32_t)WIN) ? x : -1e30f;
                    float e = fast_exp2(x);
                    psum[gq] += e;
                    pk[reg] = (__bf16)e;
                }
                *reinterpret_cast<bf16x4*>(Pw + gq * 16 * PPAD + r * PPAD + nf * 16 + g * 4) = pk;
            }
#pragma unroll
        for (int kk2 = 0; kk2 < 2; ++kk2) {
            bf16x8 pa0 = *(const bf16x8*)(Pw + r * PPAD + kk2 * 32 + g * 8);
            bf16x8 pa1 = *(const bf16x8*)(Pw + 16 * PPAD + r * PPAD + kk2 * 32 + g * 8);
            int sw = kk2 ? swz1 : swz0;
#pragma unroll
            for (int nf2 = 0; nf2 < 4; ++nf2) {
                bf16x8 vf = *(const bf16x8*)(Vl + nf2 * 1024 + r * 64 + sw);
                o[0][nf2] = __builtin_amdgcn_mfma_f32_16x16x32_bf16(vf, pa0, o[0][nf2], 0, 0, 0);
                o[1][nf2] = __builtin_amdgcn_mfma_f32_16x16x32_bf16(vf, pa1, o[1][nf2], 0, 0, 0);
            }
        }
    };

    const int kb0 = (q0 >= 256) ? (q0 - 256) : 0;
    const int nt = (q0 + 64 - kb0) / 64 + 1;    // up to 6 tiles; keys [kb0, q0+128)
    stage(0, kb0);
    __syncthreads();
    for (int tt = 0; tt < nt; ++tt) {
        int kbase = kb0 + tt * 64;
        if (tt + 1 < nt) stage((tt + 1) & 1, kbase + 64);
        // wave-level full-mask skip (exact):
        //  - first tile (keys [q0-256,q0-192)) fully masked for waves 2,3 (iq-j >= 257)
        //  - last tile (keys [q0+64,q0+128)) fully masked for waves 0,1 (j > iq)
        bool skip = (tt == 0 && q0 >= 256 && w >= 2) || (tt == nt - 1 && w < 2);
        if (!skip) tile(tt & 1, kbase);
        __syncthreads();
    }

#pragma unroll
    for (int gq = 0; gq < 2; ++gq) {
        psum[gq] += __shfl_xor(psum[gq], 16, 64);
        psum[gq] += __shfl_xor(psum[gq], 32, 64);
        float linv = 1.0f / psum[gq];
        int s = q0 + w * 32 + gq * 16 + r;
#pragma unroll
        for (int nf2 = 0; nf2 < 4; ++nf2) {
            bf16x4 pk;
#pragma unroll
            for (int reg = 0; reg < 4; ++reg) pk[reg] = (__bf16)(o[gq][nf2][reg] * linv);
            *reinterpret_cast<bf16x4*>(ctx + ((size_t)(b * S_LEN + s)) * EMB
                                       + h * 64 + nf2 * 16 + g * 4) = pk;
        }
    }
}

// ---------- output projection (r9 form) ----------
__global__ __launch_bounds__(256, 3) void gemm_out_kernel(const __bf16* __restrict__ ctxb,
                                                          const __bf16* __restrict__ wot,
                                                          const float* __restrict__ bo,
                                                          float* __restrict__ out) {
    __shared__ __align__(16) __bf16 As[2][64 * 64];
    __shared__ __align__(16) __bf16 Bs[2][128 * 64];
    int tid = threadIdx.x;
    int wg = (blockIdx.x & 7) * 64 + (blockIdx.x >> 3);   // 512 = 8 XCD x 64
    int n0 = (wg % 8) * 128, m0 = (wg / 8) * 64;

    f32x4 acc[2][4];
    f32x4 z = {0.f, 0.f, 0.f, 0.f};
#pragma unroll
    for (int i = 0; i < 2; ++i)
#pragma unroll
        for (int j = 0; j < 4; ++j) acc[i][j] = z;

    gemm_core64(ctxb, wot, EMB, m0, n0, As, Bs, acc, tid);

    const int lane = tid & 63, w = tid >> 6;
    const int wr = w >> 1, wc = w & 1, r = lane & 15, g = lane >> 4;
#pragma unroll
    for (int nf = 0; nf < 4; ++nf) {
        int n = n0 + wc * 64 + nf * 16 + r;
        float bb = bo[n];
#pragma unroll
        for (int mf = 0; mf < 2; ++mf)
#pragma unroll
            for (int reg = 0; reg < 4; ++reg) {
                int m = m0 + wr * 32 + mf * 16 + g * 4 + reg;
                out[(size_t)m * EMB + n] = acc[mf][nf][reg] + bb;
            }
    }
}

// ---------- launch ----------
extern "C" void kernel_launch(void* const* d_in, const int* in_sizes, int n_in,
                              void* d_out, int out_size, void* d_ws, size_t ws_size,
                              hipStream_t stream) {
    const float* x  = (const float*)d_in[0];
    const float* wq = (const float*)d_in[1];
    const float* bq = (const float*)d_in[2];
    const float* wk = (const float*)d_in[3];
    const float* bk = (const float*)d_in[4];
    const float* wv = (const float*)d_in[5];
    const float* bv = (const float*)d_in[6];
    const float* wo = (const float*)d_in[7];
    const float* bo = (const float*)d_in[8];
    float* out = (float*)d_out;

    char* ws = (char*)d_ws;
    __bf16* xb   = (__bf16*)ws;          ws += (size_t)MROWS * EMB * 2;           // 8 MB
    __bf16* wqt  = (__bf16*)ws;          ws += (size_t)EMB * EMB * 2;             // 2 MB
    __bf16* wkt  = (__bf16*)ws;          ws += (size_t)256 * EMB * 2;             // 0.5 MB
    __bf16* wvt  = (__bf16*)ws;          ws += (size_t)256 * EMB * 2;             // 0.5 MB
    __bf16* wot  = (__bf16*)ws;          ws += (size_t)EMB * EMB * 2;             // 2 MB
    __bf16* Qb   = (__bf16*)ws;          ws += (size_t)NB * NH * S_LEN * HD * 2;  // 8 MB
    __bf16* Kb   = (__bf16*)ws;          ws += (size_t)NB * NKV * S_LEN * HD * 2; // 2 MB
    __bf16* Vblk = (__bf16*)ws;          ws += (size_t)NB * NKV * S_LEN * HD * 2; // 2 MB
    __bf16* ctx  = (__bf16*)ws;          ws += (size_t)MROWS * EMB * 2;           // 8 MB

    prep_kernel<<<2816, 256, 0, stream>>>(x, wq, wk, wv,
                                          (u16*)xb, (u16*)wqt, (u16*)wkt, (u16*)wvt);
    gemm_qkv_kernel<<<768, 256, 0, stream>>>(xb, wqt, wkt, wvt, bq, bk, bv, Qb, Kb, Vblk);
    attn_kernel<<<768, 256, 0, stream>>>(Qb, Kb, Vblk, wo, (u16*)wot, ctx);
    gemm_out_kernel<<<512, 256, 0, stream>>>(ctx, wot, bo, out);
}

// Round 20
// 63.840 us; speedup vs baseline: 1.2333x; 1.0018x over previous
//
#include <hip/hip_runtime.h>
#include <stdint.h>

typedef unsigned short u16;
typedef __attribute__((ext_vector_type(8))) __bf16 bf16x8;
typedef __attribute__((ext_vector_type(4))) __bf16 bf16x4;
typedef __attribute__((ext_vector_type(4))) float f32x4;

#define S_LEN 2048
#define EMB   1024
#define NH    16
#define NKV   4
#define HD    64
#define WIN   256
#define NB    2
#define MROWS (NB * S_LEN)   // 4096
#define PPAD  72             // P LDS row stride (elements)

// ---------- helpers ----------
__device__ __forceinline__ u16 f2bf(float f) {
    uint32_t u = __float_as_uint(f);
    uint32_t r = (u + 0x7FFFu + ((u >> 16) & 1u)) >> 16;   // RNE
    return (u16)r;
}

__device__ __forceinline__ float fast_exp2(float x) {
#if __has_builtin(__builtin_amdgcn_exp2f)
    return __builtin_amdgcn_exp2f(x);
#else
    float r; asm("v_exp_f32 %0, %1" : "=v"(r) : "v"(x)); return r;
#endif
}

__device__ __forceinline__ void gload16(const void* g, void* l) {
    __builtin_amdgcn_global_load_lds(
        (const __attribute__((address_space(1))) uint32_t*)(uintptr_t)g,
        (__attribute__((address_space(3))) uint32_t*)(uintptr_t)l,
        16, 0, 0);
}

// ---------- weight transpose job (shared-buffer passed in) ----------
// in [R][C] f32 -> out [C][R] bf16; tile = 64 rows (r) x 32 cols (c)
__device__ __forceinline__ void transpose_job64(const float* __restrict__ in,
                                                u16* __restrict__ out,
                                                int R, int C, int bx, int by, int tid,
                                                float (*t)[33]) {
    int c0 = bx * 32, r0 = by * 64;
    int tx = tid & 31, ty = tid >> 5;   // (32, 8)
#pragma unroll
    for (int j = 0; j < 64; j += 8)
        t[ty + j][tx] = in[(size_t)(r0 + ty + j) * C + (c0 + tx)];
    __syncthreads();
#pragma unroll
    for (int j = 0; j < 32; j += 8) {
        int c = j + ty;
        uint32_t v = f2bf(t[2 * tx][c]) | ((uint32_t)f2bf(t[2 * tx + 1][c]) << 16);
        *(uint32_t*)(out + (size_t)(c0 + c) * R + r0 + 2 * tx) = v;
    }
}

// ---------- prep: x->bf16 + wq/wk/wv transposes (wo^T in attn spare blocks) ----------
// grid 2816: [0,2048) x-cvt; [2048,2560) wq^T; [2560,2688) wk^T; [2688,2816) wv^T
__global__ __launch_bounds__(256) void prep_kernel(
    const float* __restrict__ x,  const float* __restrict__ wq,
    const float* __restrict__ wk, const float* __restrict__ wv,
    u16* __restrict__ xb, u16* __restrict__ wqt, u16* __restrict__ wkt,
    u16* __restrict__ wvt) {
    __shared__ float t[64][33];
    int bid = blockIdx.x, tid = threadIdx.x;
    if (bid < 2048) {
        int i = bid * 256 + tid;                       // 8 elems each
        const float4* p = (const float4*)x + (size_t)i * 2;
        float4 a = p[0], b = p[1];
        uint4 q;
        q.x = f2bf(a.x) | ((uint32_t)f2bf(a.y) << 16);
        q.y = f2bf(a.z) | ((uint32_t)f2bf(a.w) << 16);
        q.z = f2bf(b.x) | ((uint32_t)f2bf(b.y) << 16);
        q.w = f2bf(b.z) | ((uint32_t)f2bf(b.w) << 16);
        ((uint4*)xb)[i] = q;
    } else if (bid < 2560) {
        int lb = bid - 2048;  transpose_job64(wq, wqt, EMB, EMB, lb & 31, lb >> 5, tid, t);
    } else if (bid < 2688) {
        int lb = bid - 2560;  transpose_job64(wk, wkt, EMB, 256, lb & 7, lb >> 3, tid, t);
    } else {
        int lb = bid - 2688;  transpose_job64(wv, wvt, EMB, 256, lb & 7, lb >> 3, tid, t);
    }
}

// ---------- GEMM core: BM=64 x BN=128, BK=64, 4 waves (2x2), 2-phase prefetch ----------
__device__ __forceinline__ void gemm_core64(const __bf16* __restrict__ A, const __bf16* __restrict__ Bt,
                                            int K, int m0, int n0r,
                                            __bf16 (*As)[64 * 64], __bf16 (*Bs)[128 * 64],
                                            f32x4 (&acc)[2][4], int tid) {
    const int lane = tid & 63, w = tid >> 6;
    const int wr = w >> 1, wc = w & 1;
    const int r = lane & 15, g = lane >> 4;

    auto stage = [&](int buf, int k0) {
#pragma unroll
        for (int i = 0; i < 2; ++i) {
            int chunk = (w * 2 + i) * 64 + lane;
            int row = chunk >> 3, cc = chunk & 7;
            gload16(A + (size_t)(m0 + row) * K + k0 + cc * 8, &As[buf][(w * 2 + i) * 512]);
        }
#pragma unroll
        for (int i = 0; i < 4; ++i) {
            int chunk = (w * 4 + i) * 64 + lane;
            int row = chunk >> 3, cc = chunk & 7;
            gload16(Bt + (size_t)(n0r + row) * K + k0 + cc * 8, &Bs[buf][(w * 4 + i) * 512]);
        }
    };

    stage(0, 0);
    __syncthreads();
    for (int k0 = 0; k0 < K; k0 += 64) {
        int cur = (k0 >> 6) & 1;
        if (k0 + 64 < K) stage(cur ^ 1, k0 + 64);
        bf16x8 af[2][2], bfr[4][2];
#pragma unroll
        for (int mf = 0; mf < 2; ++mf)
#pragma unroll
            for (int kk = 0; kk < 2; ++kk)
                af[mf][kk] = *(const bf16x8*)(&As[cur][(wr * 32 + mf * 16 + r) * 64 + kk * 32 + g * 8]);
#pragma unroll
        for (int nf = 0; nf < 4; ++nf)
#pragma unroll
            for (int kk = 0; kk < 2; ++kk)
                bfr[nf][kk] = *(const bf16x8*)(&Bs[cur][(wc * 64 + nf * 16 + r) * 64 + kk * 32 + g * 8]);
#pragma unroll
        for (int mf = 0; mf < 2; ++mf)
#pragma unroll
            for (int nf = 0; nf < 4; ++nf)
#pragma unroll
                for (int kk = 0; kk < 2; ++kk)
                    acc[mf][nf] = __builtin_amdgcn_mfma_f32_16x16x32_bf16(
                        af[mf][kk], bfr[nf][kk], acc[mf][nf], 0, 0, 0);
        __syncthreads();
    }
}

// ---------- QKV projection (r9 form) ----------
__global__ __launch_bounds__(256, 3) void gemm_qkv_kernel(
    const __bf16* __restrict__ xb, const __bf16* __restrict__ wqt,
    const __bf16* __restrict__ wkt, const __bf16* __restrict__ wvt,
    const float* __restrict__ bq, const float* __restrict__ bk, const float* __restrict__ bv,
    __bf16* __restrict__ Qb, __bf16* __restrict__ Kb, __bf16* __restrict__ Vblk) {
    __shared__ __align__(16) __bf16 As[2][64 * 64];
    __shared__ __align__(16) __bf16 Bs[2][128 * 64];
    int tid = threadIdx.x;
    int wg = (blockIdx.x & 7) * 96 + (blockIdx.x >> 3);   // 768 = 8 XCD x 96
    int n0 = (wg % 12) * 128, m0 = (wg / 12) * 64;

    const __bf16* Bt; int n0r; const float* bias; int mode;
    if (n0 < 1024)      { Bt = wqt; n0r = n0;        bias = bq; mode = 0; }
    else if (n0 < 1280) { Bt = wkt; n0r = n0 - 1024; bias = bk; mode = 1; }
    else                { Bt = wvt; n0r = n0 - 1280; bias = bv; mode = 2; }

    f32x4 acc[2][4];
    f32x4 z = {0.f, 0.f, 0.f, 0.f};
#pragma unroll
    for (int i = 0; i < 2; ++i)
#pragma unroll
        for (int j = 0; j < 4; ++j) acc[i][j] = z;

    gemm_core64(xb, Bt, EMB, m0, n0r, As, Bs, acc, tid);

    const int lane = tid & 63, w = tid >> 6;
    const int wr = w >> 1, wc = w & 1, r = lane & 15, g = lane >> 4;
#pragma unroll
    for (int nf = 0; nf < 4; ++nf) {
        int nn = n0r + wc * 64 + nf * 16 + r;
        float bb = bias[nn];
        int hh = nn >> 6, dd = nn & 63;
        if (mode == 2) {
            // block-tiled V: [s>>6][d][s&63]; 4 consecutive s -> 8B store
#pragma unroll
            for (int mf = 0; mf < 2; ++mf) {
                int s0 = m0 + wr * 32 + mf * 16 + g * 4;
                int bi = s0 >> 11, s = s0 & 2047;
                bf16x4 pk;
#pragma unroll
                for (int reg = 0; reg < 4; ++reg) pk[reg] = (__bf16)(acc[mf][nf][reg] + bb);
                *reinterpret_cast<bf16x4*>(Vblk + (size_t)(bi * NKV + hh) * (S_LEN * HD)
                                           + (s >> 6) * 4096 + dd * 64 + (s & 63)) = pk;
            }
        } else {
#pragma unroll
            for (int mf = 0; mf < 2; ++mf)
#pragma unroll
                for (int reg = 0; reg < 4; ++reg) {
                    int m = m0 + wr * 32 + mf * 16 + g * 4 + reg;
                    int bi = m >> 11, s = m & 2047;
                    __bf16 o = (__bf16)(acc[mf][nf][reg] + bb);
                    if (mode == 0)
                        Qb[((size_t)(bi * NH + hh) * S_LEN + s) * HD + dd] = o;
                    else
                        Kb[((size_t)(bi * NKV + hh) * S_LEN + s) * HD + dd] = o;
                }
        }
    }
}

// ---------- sliding-window flash attention: QBLK=128 + wave tile-skip + wot^T in spare blocks ----------
// 1D grid 768: bid<512 -> attn job (qb=bid&15, h=(bid>>4)&15, b=bid>>8);
//              bid>=512 -> 2 wo-transpose jobs each (512 jobs total)
__global__ __launch_bounds__(256, 3) void attn_kernel(const __bf16* __restrict__ Qb,
                                                      const __bf16* __restrict__ Kb,
                                                      const __bf16* __restrict__ Vblk,
                                                      const float* __restrict__ wo,
                                                      u16* __restrict__ wot,
                                                      __bf16* __restrict__ ctx) {
    __shared__ __align__(16) __bf16 Ks[2][64 * 64];      // [buf][row=key][d]  8KB each
    __shared__ __align__(16) __bf16 Vs[2][64 * 64];      // [buf][row=d][key]  8KB each
    __shared__ __align__(16) __bf16 Plds[4][32 * PPAD];  // per-wave P [q=32][k=64 pad]
    const int tid = threadIdx.x;
    const int bid = blockIdx.x;

    if (bid >= 512) {
        // spare blocks: wo [1024][1024] -> wot; 512 tile-jobs, 2 per block
        float (*t)[33] = reinterpret_cast<float(*)[33]>(&Ks[0][0]);   // 8.5KB <= 16KB
        int j0 = (bid - 512) * 2;
        transpose_job64(wo, wot, EMB, EMB, j0 & 31, j0 >> 5, tid, t);
        __syncthreads();
        int j1 = j0 + 1;
        transpose_job64(wo, wot, EMB, EMB, j1 & 31, j1 >> 5, tid, t);
        return;
    }

    const int lane = tid & 63, w = tid >> 6;
    const int r = lane & 15, g = lane >> 4;
    const int q0 = (bid & 15) * 128;
    const int h = (bid >> 4) & 15, b = bid >> 8;
    const int kvh = h >> 2;
    const __bf16* Kh = Kb + (size_t)(b * NKV + kvh) * S_LEN * HD;
    const __bf16* Vh = Vblk + (size_t)(b * NKV + kvh) * S_LEN * HD;
    __bf16* Pw = &Plds[w][0];

    const int n0s = w * 128 + lane;
    const int n1s = n0s + 64;
    const int srcoff0 = (n0s >> 3) * 64 + (((n0s & 7) ^ ((n0s >> 3) & 7)) * 8);
    const int srcoff1 = (n1s >> 3) * 64 + (((n1s & 7) ^ ((n1s >> 3) & 7)) * 8);
    const int dst0 = (w * 2) * 512;
    const int dst1 = dst0 + 512;

    auto stage = [&](int buf, int kbase) {
        const __bf16* Kt = Kh + (size_t)kbase * 64;
        const __bf16* Vt = Vh + (size_t)kbase * 64;
        gload16(Kt + srcoff0, &Ks[buf][dst0]);
        gload16(Kt + srcoff1, &Ks[buf][dst1]);
        gload16(Vt + srcoff0, &Vs[buf][dst0]);
        gload16(Vt + srcoff1, &Vs[buf][dst1]);
    };

    const int swz0 = ((0 * 4 + g) ^ (r & 7)) * 8;
    const int swz1 = ((1 * 4 + g) ^ (r & 7)) * 8;

    bf16x8 qf[2][2];
#pragma unroll
    for (int gq = 0; gq < 2; ++gq)
#pragma unroll
        for (int kk = 0; kk < 2; ++kk)
            qf[gq][kk] = *(const bf16x8*)(Qb + ((size_t)(b * NH + h) * S_LEN
                                          + q0 + w * 32 + gq * 16 + r) * HD + kk * 32 + g * 8);

    f32x4 z = {0.f, 0.f, 0.f, 0.f};
    f32x4 o[2][4];
#pragma unroll
    for (int gq = 0; gq < 2; ++gq)
#pragma unroll
        for (int i = 0; i < 4; ++i) o[gq][i] = z;
    float psum[2] = {0.f, 0.f};

    const float SC = 0.18033688011112042f;   // D^-0.5 * log2(e)
    int iq[2];
#pragma unroll
    for (int gq = 0; gq < 2; ++gq) iq[gq] = q0 + w * 32 + gq * 16 + r;

    auto tile = [&](int buf, int kbase) {
        const __bf16* Kl = &Ks[buf][0];
        const __bf16* Vl = &Vs[buf][0];
        f32x4 sa[2][4];
#pragma unroll
        for (int gq = 0; gq < 2; ++gq)
#pragma unroll
            for (int nf = 0; nf < 4; ++nf) sa[gq][nf] = z;
#pragma unroll
        for (int nf = 0; nf < 4; ++nf) {
            bf16x8 kf0 = *(const bf16x8*)(Kl + nf * 1024 + r * 64 + swz0);
            bf16x8 kf1 = *(const bf16x8*)(Kl + nf * 1024 + r * 64 + swz1);
            sa[0][nf] = __builtin_amdgcn_mfma_f32_16x16x32_bf16(kf0, qf[0][0], sa[0][nf], 0, 0, 0);
            sa[1][nf] = __builtin_amdgcn_mfma_f32_16x16x32_bf16(kf0, qf[1][0], sa[1][nf], 0, 0, 0);
            sa[0][nf] = __builtin_amdgcn_mfma_f32_16x16x32_bf16(kf1, qf[0][1], sa[0][nf], 0, 0, 0);
            sa[1][nf] = __builtin_amdgcn_mfma_f32_16x16x32_bf16(kf1, qf[1][1], sa[1][nf], 0, 0, 0);
        }
#pragma unroll
        for (int gq = 0; gq < 2; ++gq)
#pragma unroll
            for (int nf = 0; nf < 4; ++nf) {
                int jb = kbase + nf * 16 + g * 4;
                bf16x4 pk;
#pragma unroll
                for (int reg = 0; reg < 4; ++reg) {
                    float x = sa[gq][nf][reg] * SC;
                    uint32_t d = (uint32_t)(iq[gq] - (jb + reg));   // valid iff 0 <= iq-j <= WIN
                    x = (d <= (uint32_t)WIN) ? x : -1e30f;
                    float e = fast_exp2(x);
                    psum[gq] += e;
                    pk[reg] = (__bf16)e;
                }
                *reinterpret_cast<bf16x4*>(Pw + gq * 16 * PPAD + r * PPAD + nf * 16 + g * 4) = pk;
            }
#pragma unroll
        for (int kk2 = 0; kk2 < 2; ++kk2) {
            bf16x8 pa0 = *(const bf16x8*)(Pw + r * PPAD + kk2 * 32 + g * 8);
            bf16x8 pa1 = *(const bf16x8*)(Pw + 16 * PPAD + r * PPAD + kk2 * 32 + g * 8);
            int sw = kk2 ? swz1 : swz0;
#pragma unroll
            for (int nf2 = 0; nf2 < 4; ++nf2) {
                bf16x8 vf = *(const bf16x8*)(Vl + nf2 * 1024 + r * 64 + sw);
                o[0][nf2] = __builtin_amdgcn_mfma_f32_16x16x32_bf16(vf, pa0, o[0][nf2], 0, 0, 0);
                o[1][nf2] = __builtin_amdgcn_mfma_f32_16x16x32_bf16(vf, pa1, o[1][nf2], 0, 0, 0);
            }
        }
    };

    const int kb0 = (q0 >= 256) ? (q0 - 256) : 0;
    const int nt = (q0 + 64 - kb0) / 64 + 1;    // up to 6 tiles; keys [kb0, q0+128)
    stage(0, kb0);
    __syncthreads();
    for (int tt = 0; tt < nt; ++tt) {
        int kbase = kb0 + tt * 64;
        if (tt + 1 < nt) stage((tt + 1) & 1, kbase + 64);
        // wave-level full-mask skip (exact):
        //  - first tile (keys [q0-256,q0-192)) fully masked for waves 2,3 (iq-j >= 257)
        //  - last tile (keys [q0+64,q0+128)) fully masked for waves 0,1 (j > iq)
        bool skip = (tt == 0 && q0 >= 256 && w >= 2) || (tt == nt - 1 && w < 2);
        if (!skip) tile(tt & 1, kbase);
        __syncthreads();
    }

#pragma unroll
    for (int gq = 0; gq < 2; ++gq) {
        psum[gq] += __shfl_xor(psum[gq], 16, 64);
        psum[gq] += __shfl_xor(psum[gq], 32, 64);
        float linv = 1.0f / psum[gq];
        int s = q0 + w * 32 + gq * 16 + r;
#pragma unroll
        for (int nf2 = 0; nf2 < 4; ++nf2) {
            bf16x4 pk;
#pragma unroll
            for (int reg = 0; reg < 4; ++reg) pk[reg] = (__bf16)(o[gq][nf2][reg] * linv);
            *reinterpret_cast<bf16x4*>(ctx + ((size_t)(b * S_LEN + s)) * EMB
                                       + h * 64 + nf2 * 16 + g * 4) = pk;
        }
    }
}

// ---------- output projection (r9 form) ----------
__global__ __launch_bounds__(256, 3) void gemm_out_kernel(const __bf16* __restrict__ ctxb,
                                                          const __bf16* __restrict__ wot,
                                                          const float* __restrict__ bo,
                                                          float* __restrict__ out) {
    __shared__ __align__(16) __bf16 As[2][64 * 64];
    __shared__ __align__(16) __bf16 Bs[2][128 * 64];
    int tid = threadIdx.x;
    int wg = (blockIdx.x & 7) * 64 + (blockIdx.x >> 3);   // 512 = 8 XCD x 64
    int n0 = (wg % 8) * 128, m0 = (wg / 8) * 64;

    f32x4 acc[2][4];
    f32x4 z = {0.f, 0.f, 0.f, 0.f};
#pragma unroll
    for (int i = 0; i < 2; ++i)
#pragma unroll
        for (int j = 0; j < 4; ++j) acc[i][j] = z;

    gemm_core64(ctxb, wot, EMB, m0, n0, As, Bs, acc, tid);

    const int lane = tid & 63, w = tid >> 6;
    const int wr = w >> 1, wc = w & 1, r = lane & 15, g = lane >> 4;
#pragma unroll
    for (int nf = 0; nf < 4; ++nf) {
        int n = n0 + wc * 64 + nf * 16 + r;
        float bb = bo[n];
#pragma unroll
        for (int mf = 0; mf < 2; ++mf)
#pragma unroll
            for (int reg = 0; reg < 4; ++reg) {
                int m = m0 + wr * 32 + mf * 16 + g * 4 + reg;
                out[(size_t)m * EMB + n] = acc[mf][nf][reg] + bb;
            }
    }
}

// ---------- launch ----------
extern "C" void kernel_launch(void* const* d_in, const int* in_sizes, int n_in,
                              void* d_out, int out_size, void* d_ws, size_t ws_size,
                              hipStream_t stream) {
    const float* x  = (const float*)d_in[0];
    const float* wq = (const float*)d_in[1];
    const float* bq = (const float*)d_in[2];
    const float* wk = (const float*)d_in[3];
    const float* bk = (const float*)d_in[4];
    const float* wv = (const float*)d_in[5];
    const float* bv = (const float*)d_in[6];
    const float* wo = (const float*)d_in[7];
    const float* bo = (const float*)d_in[8];
    float* out = (float*)d_out;

    char* ws = (char*)d_ws;
    __bf16* xb   = (__bf16*)ws;          ws += (size_t)MROWS * EMB * 2;           // 8 MB
    __bf16* wqt  = (__bf16*)ws;          ws += (size_t)EMB * EMB * 2;             // 2 MB
    __bf16* wkt  = (__bf16*)ws;          ws += (size_t)256 * EMB * 2;             // 0.5 MB
    __bf16* wvt  = (__bf16*)ws;          ws += (size_t)256 * EMB * 2;             // 0.5 MB
    __bf16* wot  = (__bf16*)ws;          ws += (size_t)EMB * EMB * 2;             // 2 MB
    __bf16* Qb   = (__bf16*)ws;          ws += (size_t)NB * NH * S_LEN * HD * 2;  // 8 MB
    __bf16* Kb   = (__bf16*)ws;          ws += (size_t)NB * NKV * S_LEN * HD * 2; // 2 MB
    __bf16* Vblk = (__bf16*)ws;          ws += (size_t)NB * NKV * S_LEN * HD * 2; // 2 MB
    __bf16* ctx  = (__bf16*)ws;          ws += (size_t)MROWS * EMB * 2;           // 8 MB

    prep_kernel<<<2816, 256, 0, stream>>>(x, wq, wk, wv,
                                          (u16*)xb, (u16*)wqt, (u16*)wkt, (u16*)wvt);
    gemm_qkv_kernel<<<768, 256, 0, stream>>>(xb, wqt, wkt, wvt, bq, bk, bv, Qb, Kb, Vblk);
    attn_kernel<<<768, 256, 0, stream>>>(Qb, Kb, Vblk, wo, (u16*)wot, ctx);
    gemm_out_kernel<<<512, 256, 0, stream>>>(ctx, wot, bo, out);
}